// Round 5
// baseline (254.485 us; speedup 1.0000x reference)
//
#include <hip/hip_runtime.h>
#include <stdint.h>

typedef _Float16 f16;
typedef _Float16 f16x4 __attribute__((ext_vector_type(4)));
typedef _Float16 f16x8 __attribute__((ext_vector_type(8)));
typedef float f32x4 __attribute__((ext_vector_type(4)));

#define K_DIM 1600
#define NF_DIM 6400
#define KPAD 1664   // 26 tiles of 64
#define NKT 26
#define KPB (KPAD * 2)  // row stride in bytes = 3328

// ---------- async global->LDS 16B copy ----------
__device__ __forceinline__ void async_copy16(const void* g, void* l) {
    __builtin_amdgcn_global_load_lds(
        (const __attribute__((address_space(1))) void*)(uintptr_t)g,
        (__attribute__((address_space(3))) void*)(uint32_t)(uintptr_t)l,
        16, 0, 0);
}

// ---------- block-wide max (256 threads = 4 waves) ----------
__device__ __forceinline__ float blockMax(float v, float* sm) {
#pragma unroll
    for (int off = 32; off > 0; off >>= 1)
        v = fmaxf(v, __shfl_down(v, off, 64));
    int wid = threadIdx.x >> 6, lane = threadIdx.x & 63;
    if (lane == 0) sm[wid] = v;
    __syncthreads();
    if (threadIdx.x == 0) {
        float m = sm[0];
        for (int i = 1; i < (int)(blockDim.x >> 6); ++i) m = fmaxf(m, sm[i]);
        sm[0] = m;
    }
    __syncthreads();
    return sm[0];
}

// ---------- per-token activation quant ----------
__global__ void quant_x_kernel(const float* __restrict__ x, f16* __restrict__ qx,
                               float* __restrict__ ax) {
    __shared__ float sm[4];
    size_t row = blockIdx.x;
    const float* xr = x + row * (size_t)K_DIM;
    float m = 0.f;
    const int n4 = K_DIM >> 2;
    for (int i = threadIdx.x; i < n4; i += blockDim.x) {
        float4 v = ((const float4*)xr)[i];
        m = fmaxf(fmaxf(fmaxf(fabsf(v.x), fabsf(v.y)), fmaxf(fabsf(v.z), fabsf(v.w))), m);
    }
    m = blockMax(m, sm);
    float s = 127.0f / (m + 1e-6f);
    if (threadIdx.x == 0) ax[row] = 1.0f / (s + 1e-6f);
    f16* qr = qx + row * (size_t)KPAD;
    for (int i = threadIdx.x; i < n4; i += blockDim.x) {
        float4 v = ((const float4*)xr)[i];
        f16x4 q;
        q[0] = (f16)rintf(v.x * s);
        q[1] = (f16)rintf(v.y * s);
        q[2] = (f16)rintf(v.z * s);
        q[3] = (f16)rintf(v.w * s);
        *(f16x4*)&qr[i * 4] = q;
    }
    if (threadIdx.x < 16) {
        f16x4 z = {};
        *(f16x4*)&qr[K_DIM + threadIdx.x * 4] = z;
    }
}

// ---------- per-row weight scale ----------
__global__ void wscale_kernel(const float* __restrict__ w, float* __restrict__ sw) {
    __shared__ float sm[4];
    size_t k = blockIdx.x;
    const float* wr = w + k * (size_t)NF_DIM;
    float m = 0.f;
    const int n4 = NF_DIM >> 2;
    for (int i = threadIdx.x; i < n4; i += blockDim.x) {
        float4 v = ((const float4*)wr)[i];
        m = fmaxf(fmaxf(fmaxf(fabsf(v.x), fabsf(v.y)), fmaxf(fabsf(v.z), fabsf(v.w))), m);
    }
    m = blockMax(m, sm);
    if (threadIdx.x == 0) sw[k] = 127.0f / (m + 1e-6f);
}

// ---------- quantize + transpose weight -> wqt[N][KPAD] fp16 ----------
__global__ void wtq_kernel(const float* __restrict__ w, const float* __restrict__ sw,
                           f16* __restrict__ wqt) {
    __shared__ f16 t[64][80];
    int k0 = blockIdx.x * 64;
    int f0 = blockIdx.y * 64;
    int tid = threadIdx.x;
    if (k0 >= K_DIM) {
        int fr = tid >> 2;
        int ch = (tid & 3) << 4;
        float4 z = {};
        float4* dst = (float4*)&wqt[(size_t)(f0 + fr) * KPAD + k0 + ch];
        dst[0] = z;
        dst[1] = z;
        return;
    }
    int rr = tid >> 4;
    int cc = (tid & 15) << 2;
#pragma unroll
    for (int i = 0; i < 4; ++i) {
        int r = rr + i * 16;
        float s = sw[k0 + r];
        float inv = 1.0f / (s + 1e-6f);
        float4 v = *(const float4*)&w[(size_t)(k0 + r) * NF_DIM + f0 + cc];
        t[cc + 0][r] = (f16)(rintf(v.x * s) * inv);
        t[cc + 1][r] = (f16)(rintf(v.y * s) * inv);
        t[cc + 2][r] = (f16)(rintf(v.z * s) * inv);
        t[cc + 3][r] = (f16)(rintf(v.w * s) * inv);
    }
    __syncthreads();
    int fr = tid >> 2;
    int ch = (tid & 3) << 4;
    const float4* src = (const float4*)&t[fr][ch];
    float4* dst = (float4*)&wqt[(size_t)(f0 + fr) * KPAD + k0 + ch];
    dst[0] = src[0];
    dst[1] = src[1];
}

// ---------- 256x256 8-phase GEMM, pipelined fragment reads (counted lgkmcnt) ----------
__global__ __launch_bounds__(512, 1) void gemm256(
    const f16* __restrict__ A,    // [M][KPAD]
    const f16* __restrict__ Bt,   // [N][KPAD]
    const float* __restrict__ ax,
    const float* __restrict__ bias,
    float* __restrict__ C, int M, int N) {
    extern __shared__ char lds[];
    // buf b at lds + b*65536: A-lo @+0, A-hi @+16384, B-lo @+32768, B-hi @+49152

    const int tid = threadIdx.x;
    const int lane = tid & 63;
    const int wv = tid >> 6;   // 0..7
    const int wm = wv >> 2;    // 0..1
    const int wn = wv & 3;     // 0..3
    const int lr = lane & 15;
    const int lg = lane >> 4;

    const int nTn = N / 256;            // 25
    const int bid = blockIdx.x;
    const int cpx = gridDim.x >> 3;
    const int swz = (bid & 7) * cpx + (bid >> 3);
    const int tm = swz / nTn, tn = swz % nTn;
    const size_t m0 = (size_t)tm * 256, n0 = (size_t)tn * 256;

    // ---- per-thread precomputed staging pointers ----
    const int srow8 = lane >> 3;
    const int sslot = (lane & 7) ^ srow8;
    const char* pAlo = (const char*)A + (m0 + (size_t)(wv * 16 + srow8)) * KPB + sslot * 16;
    const char* pAhi = pAlo + (size_t)128 * KPB;
    const char* pBlo = (const char*)Bt + (n0 + (size_t)(wv * 16 + srow8)) * KPB + sslot * 16;
    const char* pBhi = pBlo + (size_t)128 * KPB;
    const int L0 = wv * 2048 + lane * 16;  // linear LDS dest (j=0); j=1 at +1024

#define ST(gp, t, roff)                                       \
    {                                                         \
        const char* g_ = (gp) + (size_t)(t) * 128;            \
        async_copy16(g_, lds + (roff) + L0);                  \
        async_copy16(g_ + 8 * KPB, lds + (roff) + L0 + 1024); \
    }

    // ---- per-thread LDS read constants (swizzle folded) ----
    const int swz0 = ((lg) ^ (lr & 7)) << 4;
    const int swz1 = ((4 + lg) ^ (lr & 7)) << 4;
    const int rbA = (wm * 128 + lr) * 128;
    const int rbB = 32768 + (wn * 64 + lr) * 128;

#define RD_ALO(bsel)                                                 \
    {                                                                \
        const char* p0_ = lds + (bsel) + rbA + swz0;                 \
        const char* p1_ = lds + (bsel) + rbA + swz1;                 \
        _Pragma("unroll") for (int mi_ = 0; mi_ < 4; ++mi_) {        \
            alo[mi_][0] = *(const f16x8*)(p0_ + mi_ * 2048);         \
            alo[mi_][1] = *(const f16x8*)(p1_ + mi_ * 2048);         \
        }                                                            \
    }
#define RD_AHI(bsel)                                                 \
    {                                                                \
        const char* p0_ = lds + (bsel) + rbA + swz0 + 8192;          \
        const char* p1_ = lds + (bsel) + rbA + swz1 + 8192;          \
        _Pragma("unroll") for (int mi_ = 0; mi_ < 4; ++mi_) {        \
            ahi[mi_][0] = *(const f16x8*)(p0_ + mi_ * 2048);         \
            ahi[mi_][1] = *(const f16x8*)(p1_ + mi_ * 2048);         \
        }                                                            \
    }
#define RD_BLO(bsel)                                                 \
    {                                                                \
        const char* p0_ = lds + (bsel) + rbB + swz0;                 \
        const char* p1_ = lds + (bsel) + rbB + swz1;                 \
        _Pragma("unroll") for (int ni_ = 0; ni_ < 2; ++ni_) {        \
            blo[ni_][0] = *(const f16x8*)(p0_ + ni_ * 2048);         \
            blo[ni_][1] = *(const f16x8*)(p1_ + ni_ * 2048);         \
        }                                                            \
    }
#define RD_BHI(bsel)                                                 \
    {                                                                \
        const char* p0_ = lds + (bsel) + rbB + swz0 + 4096;          \
        const char* p1_ = lds + (bsel) + rbB + swz1 + 4096;          \
        _Pragma("unroll") for (int ni_ = 0; ni_ < 2; ++ni_) {        \
            bhi[ni_][0] = *(const f16x8*)(p0_ + ni_ * 2048);         \
            bhi[ni_][1] = *(const f16x8*)(p1_ + ni_ * 2048);         \
        }                                                            \
    }

#define BARRIER __builtin_amdgcn_s_barrier()
#define LGKM(n) asm volatile("s_waitcnt lgkmcnt(" #n ")" ::: "memory")
#define SB0 __builtin_amdgcn_sched_barrier(0)
#define VM4 asm volatile("s_waitcnt vmcnt(4)" ::: "memory")

#define MF(AF, BF, R0, C0)                                                        \
    {                                                                             \
        __builtin_amdgcn_s_setprio(1);                                            \
        _Pragma("unroll") for (int mi_ = 0; mi_ < 4; ++mi_)                       \
        _Pragma("unroll") for (int ni_ = 0; ni_ < 2; ++ni_)                       \
        _Pragma("unroll") for (int kk_ = 0; kk_ < 2; ++kk_)                       \
            acc[(R0) + mi_][(C0) + ni_] = __builtin_amdgcn_mfma_f32_16x16x32_f16( \
                AF[mi_][kk_], BF[ni_][kk_], acc[(R0) + mi_][(C0) + ni_], 0, 0, 0);\
        __builtin_amdgcn_s_setprio(0);                                            \
    }

    f32x4 acc[8][4] = {};
    f16x8 alo[4][2], ahi[4][2], blo[2][2], bhi[2][2];
    const int b0 = 0, b1 = 65536;

    // ---- prologue: tile0 full + tile1 B halves; pre-read PH1 fragments ----
    ST(pAlo, 0, b0 + 0);
    ST(pAhi, 0, b0 + 16384);
    ST(pBlo, 0, b0 + 32768);
    ST(pBhi, 0, b0 + 49152);
    ST(pBlo, 1, b1 + 32768);
    ST(pBhi, 1, b1 + 49152);
    VM4;      // tile0's 8 loads retired
    BARRIER;  // all waves' tile0 loads landed
    RD_ALO(b0);
    RD_BLO(b0);

    for (int i = 0; i < NKT / 2; ++i) {
        const int t1s = 2 * i + 1;
        const int tp2 = (2 * i + 2 < NKT) ? 2 * i + 2 : NKT - 1;
        const int tp3 = (2 * i + 3 < NKT) ? 2 * i + 3 : NKT - 1;

        // ===== PH1: pre-read bhi(b0); MFMA Q0 = alo·blo =====
        RD_BHI(b0);
        ST(pAlo, t1s, b1 + 0);
        BARRIER; LGKM(4); SB0;       // alo/blo done; bhi(4) outstanding
        MF(alo, blo, 0, 0);
        BARRIER;

        // ===== PH2: pre-read ahi(b0); MFMA Q3 = alo·bhi =====
        RD_AHI(b0);
        ST(pAhi, t1s, b1 + 16384);
        BARRIER; LGKM(8); SB0;       // bhi done; ahi(8) outstanding
        MF(alo, bhi, 0, 2);
        BARRIER;

        // ===== PH3: (no reads); MFMA Q1 = ahi·blo =====
        ST(pBlo, tp2, b0 + 32768);
        BARRIER; LGKM(0); SB0;       // ahi done
        MF(ahi, blo, 4, 0);
        BARRIER;

        // ===== PH4: vmcnt(4)+barrier -> b1 landed; read alo/blo(b1) overlapped w/ Q2 =====
        ST(pBhi, tp2, b0 + 49152);
        VM4;                          // per-wave: retires b1's 4 half-tiles
        BARRIER;                      // all waves passed VM4 -> b1 globally complete
        RD_ALO(b1);
        RD_BLO(b1);
        SB0;                          // keep reads issued before MFMA cluster
        MF(ahi, bhi, 4, 2);           // no lgkm wait: ahi/bhi already drained
        BARRIER;

        // ===== PH5: pre-read bhi(b1); MFMA Q0(t1) =====
        RD_BHI(b1);
        ST(pAlo, tp2, b0 + 0);
        BARRIER; LGKM(4); SB0;       // alo/blo(b1) done
        MF(alo, blo, 0, 0);
        BARRIER;

        // ===== PH6: pre-read ahi(b1); MFMA Q3(t1) =====
        RD_AHI(b1);
        ST(pAhi, tp2, b0 + 16384);
        BARRIER; LGKM(8); SB0;
        MF(alo, bhi, 0, 2);
        BARRIER;

        // ===== PH7: (no reads); MFMA Q1(t1) =====
        ST(pBlo, tp3, b1 + 32768);
        BARRIER; LGKM(0); SB0;
        MF(ahi, blo, 4, 0);
        BARRIER;

        // ===== PH8: vmcnt(4)+barrier -> b0 landed; read alo/blo(b0) overlapped w/ Q2 =====
        ST(pBhi, tp3, b1 + 49152);
        VM4;
        BARRIER;
        RD_ALO(b0);
        RD_BLO(b0);
        SB0;
        MF(ahi, bhi, 4, 2);
        BARRIER;
    }
    asm volatile("s_waitcnt vmcnt(0) lgkmcnt(0)" ::: "memory");
    __syncthreads();

    // ---- epilogue: LDS transpose -> float4 stores ----
    const float4 b4 = *(const float4*)&bias[n0 + lane * 4];
    float* wbase = (float*)lds + wv * 1088;  // 16 rows x 68 f32
#pragma unroll
    for (int mi = 0; mi < 8; ++mi) {
        __syncthreads();
#pragma unroll
        for (int ni = 0; ni < 4; ++ni)
#pragma unroll
            for (int j = 0; j < 4; ++j)
                wbase[(lg * 4 + j) * 68 + ni * 16 + lr] = acc[mi][ni][j];
        __syncthreads();
#pragma unroll
        for (int k = 0; k < 4; ++k) {
            int rr = wv * 4 + k;        // 0..31
            int wmp = rr >> 4, r16 = rr & 15;
            size_t mg = m0 + wmp * 128 + mi * 16 + r16;
            float axv = ax[mg];
            int wvp = wmp * 4 + (lane >> 4);
            float4 v = *(const float4*)((const float*)lds + wvp * 1088 + r16 * 68 + (lane & 15) * 4);
            float4 o;
            o.x = v.x * axv + b4.x;
            o.y = v.y * axv + b4.y;
            o.z = v.z * axv + b4.z;
            o.w = v.w * axv + b4.w;
            *(float4*)&C[mg * (size_t)N + n0 + lane * 4] = o;
        }
    }
}

extern "C" void kernel_launch(void* const* d_in, const int* in_sizes, int n_in,
                              void* d_out, int out_size, void* d_ws, size_t ws_size,
                              hipStream_t stream) {
    const float* x = (const float*)d_in[0];
    const float* w = (const float*)d_in[1];
    const float* bias = (const float*)d_in[2];
    float* out = (float*)d_out;

    const int M = in_sizes[0] / K_DIM;  // 8192
    const int N = NF_DIM;

    char* ws = (char*)d_ws;
    f16* qx = (f16*)ws;
    f16* wqt = (f16*)(ws + (size_t)M * KPAD * 2);
    float* ax = (float*)(ws + (size_t)M * KPAD * 2 + (size_t)N * KPAD * 2);
    float* sw = ax + M;

    quant_x_kernel<<<M, 256, 0, stream>>>(x, qx, ax);
    wscale_kernel<<<K_DIM, 256, 0, stream>>>(w, sw);
    wtq_kernel<<<dim3(KPAD / 64, NF_DIM / 64), 256, 0, stream>>>(w, sw, wqt);

    (void)hipFuncSetAttribute((const void*)gemm256,
                              hipFuncAttributeMaxDynamicSharedMemorySize, 131072);
    gemm256<<<(M / 256) * (N / 256), 512, 131072, stream>>>(qx, wqt, ax, bias, out, M, N);
}

// Round 6
// 237.848 us; speedup vs baseline: 1.0699x; 1.0699x over previous
//
#include <hip/hip_runtime.h>
#include <stdint.h>

typedef _Float16 f16;
typedef _Float16 f16x4 __attribute__((ext_vector_type(4)));
typedef _Float16 f16x8 __attribute__((ext_vector_type(8)));
typedef float f32x4 __attribute__((ext_vector_type(4)));

#define K_DIM 1600
#define NF_DIM 6400
#define KPAD 1664   // 26 tiles of 64
#define NKT 26
#define KPB (KPAD * 2)  // row stride in bytes = 3328

// ---------- async global->LDS 16B copy ----------
__device__ __forceinline__ void async_copy16(const void* g, void* l) {
    __builtin_amdgcn_global_load_lds(
        (const __attribute__((address_space(1))) void*)(uintptr_t)g,
        (__attribute__((address_space(3))) void*)(uint32_t)(uintptr_t)l,
        16, 0, 0);
}

// ---------- block-wide max (256 threads = 4 waves) ----------
__device__ __forceinline__ float blockMax(float v, float* sm) {
#pragma unroll
    for (int off = 32; off > 0; off >>= 1)
        v = fmaxf(v, __shfl_down(v, off, 64));
    int wid = threadIdx.x >> 6, lane = threadIdx.x & 63;
    if (lane == 0) sm[wid] = v;
    __syncthreads();
    if (threadIdx.x == 0) {
        float m = sm[0];
        for (int i = 1; i < (int)(blockDim.x >> 6); ++i) m = fmaxf(m, sm[i]);
        sm[0] = m;
    }
    __syncthreads();
    return sm[0];
}

// ---------- per-token activation quant ----------
__global__ void quant_x_kernel(const float* __restrict__ x, f16* __restrict__ qx,
                               float* __restrict__ ax) {
    __shared__ float sm[4];
    size_t row = blockIdx.x;
    const float* xr = x + row * (size_t)K_DIM;
    float m = 0.f;
    const int n4 = K_DIM >> 2;
    for (int i = threadIdx.x; i < n4; i += blockDim.x) {
        float4 v = ((const float4*)xr)[i];
        m = fmaxf(fmaxf(fmaxf(fabsf(v.x), fabsf(v.y)), fmaxf(fabsf(v.z), fabsf(v.w))), m);
    }
    m = blockMax(m, sm);
    float s = 127.0f / (m + 1e-6f);
    if (threadIdx.x == 0) ax[row] = 1.0f / (s + 1e-6f);
    f16* qr = qx + row * (size_t)KPAD;
    for (int i = threadIdx.x; i < n4; i += blockDim.x) {
        float4 v = ((const float4*)xr)[i];
        f16x4 q;
        q[0] = (f16)rintf(v.x * s);
        q[1] = (f16)rintf(v.y * s);
        q[2] = (f16)rintf(v.z * s);
        q[3] = (f16)rintf(v.w * s);
        *(f16x4*)&qr[i * 4] = q;
    }
    if (threadIdx.x < 16) {
        f16x4 z = {};
        *(f16x4*)&qr[K_DIM + threadIdx.x * 4] = z;
    }
}

// ---------- per-row weight scale ----------
__global__ void wscale_kernel(const float* __restrict__ w, float* __restrict__ sw) {
    __shared__ float sm[4];
    size_t k = blockIdx.x;
    const float* wr = w + k * (size_t)NF_DIM;
    float m = 0.f;
    const int n4 = NF_DIM >> 2;
    for (int i = threadIdx.x; i < n4; i += blockDim.x) {
        float4 v = ((const float4*)wr)[i];
        m = fmaxf(fmaxf(fmaxf(fabsf(v.x), fabsf(v.y)), fmaxf(fabsf(v.z), fabsf(v.w))), m);
    }
    m = blockMax(m, sm);
    if (threadIdx.x == 0) sw[k] = 127.0f / (m + 1e-6f);
}

// ---------- quantize + transpose weight -> wqt[N][KPAD] fp16 ----------
__global__ void wtq_kernel(const float* __restrict__ w, const float* __restrict__ sw,
                           f16* __restrict__ wqt) {
    __shared__ f16 t[64][80];
    int k0 = blockIdx.x * 64;
    int f0 = blockIdx.y * 64;
    int tid = threadIdx.x;
    if (k0 >= K_DIM) {
        int fr = tid >> 2;
        int ch = (tid & 3) << 4;
        float4 z = {};
        float4* dst = (float4*)&wqt[(size_t)(f0 + fr) * KPAD + k0 + ch];
        dst[0] = z;
        dst[1] = z;
        return;
    }
    int rr = tid >> 4;
    int cc = (tid & 15) << 2;
#pragma unroll
    for (int i = 0; i < 4; ++i) {
        int r = rr + i * 16;
        float s = sw[k0 + r];
        float inv = 1.0f / (s + 1e-6f);
        float4 v = *(const float4*)&w[(size_t)(k0 + r) * NF_DIM + f0 + cc];
        t[cc + 0][r] = (f16)(rintf(v.x * s) * inv);
        t[cc + 1][r] = (f16)(rintf(v.y * s) * inv);
        t[cc + 2][r] = (f16)(rintf(v.z * s) * inv);
        t[cc + 3][r] = (f16)(rintf(v.w * s) * inv);
    }
    __syncthreads();
    int fr = tid >> 2;
    int ch = (tid & 3) << 4;
    const float4* src = (const float4*)&t[fr][ch];
    float4* dst = (float4*)&wqt[(size_t)(f0 + fr) * KPAD + k0 + ch];
    dst[0] = src[0];
    dst[1] = src[1];
}

// ---------- 256x256 8-phase GEMM, kk-split pipelined fragments ----------
// Per phase: 16 MFMA (one A-piece x both B-pieces of one kk); next piece's
// ds_reads issued in-phase with exact counted lgkmcnt (never drained to 0
// except implicit). Staging/vmcnt ledger identical to round 4.
__global__ __launch_bounds__(512, 1) void gemm256(
    const f16* __restrict__ A,    // [M][KPAD]
    const f16* __restrict__ Bt,   // [N][KPAD]
    const float* __restrict__ ax,
    const float* __restrict__ bias,
    float* __restrict__ C, int M, int N) {
    extern __shared__ char lds[];
    // buf b at lds + b*65536: A-lo @+0, A-hi @+16384, B-lo @+32768, B-hi @+49152

    const int tid = threadIdx.x;
    const int lane = tid & 63;
    const int wv = tid >> 6;   // 0..7
    const int wm = wv >> 2;    // 0..1
    const int wn = wv & 3;     // 0..3
    const int lr = lane & 15;
    const int lg = lane >> 4;

    const int nTn = N / 256;            // 25
    const int bid = blockIdx.x;
    const int cpx = gridDim.x >> 3;
    const int swz = (bid & 7) * cpx + (bid >> 3);
    const int tm = swz / nTn, tn = swz % nTn;
    const size_t m0 = (size_t)tm * 256, n0 = (size_t)tn * 256;

    // ---- per-thread precomputed staging pointers ----
    const int srow8 = lane >> 3;
    const int sslot = (lane & 7) ^ srow8;
    const char* pAlo = (const char*)A + (m0 + (size_t)(wv * 16 + srow8)) * KPB + sslot * 16;
    const char* pAhi = pAlo + (size_t)128 * KPB;
    const char* pBlo = (const char*)Bt + (n0 + (size_t)(wv * 16 + srow8)) * KPB + sslot * 16;
    const char* pBhi = pBlo + (size_t)128 * KPB;
    const int L0 = wv * 2048 + lane * 16;  // linear LDS dest (j=0); j=1 at +1024

#define ST(gp, t, roff)                                       \
    {                                                         \
        const char* g_ = (gp) + (size_t)(t) * 128;            \
        async_copy16(g_, lds + (roff) + L0);                  \
        async_copy16(g_ + 8 * KPB, lds + (roff) + L0 + 1024); \
    }

    // ---- per-thread LDS read constants (swizzle folded) ----
    const int swz0 = ((lg) ^ (lr & 7)) << 4;       // kk=0 chunk
    const int swz1 = ((4 + lg) ^ (lr & 7)) << 4;   // kk=1 chunk
    const int rbA = (wm * 128 + lr) * 128;
    const int rbB = 32768 + (wn * 64 + lr) * 128;

    // A piece: 4 x ds_read_b128 (rows mi*16 apart); rowoff 0=lo, 8192=hi
#define RD_A(dst, bsel, rowoff, sz)                                     \
    {                                                                   \
        const char* p_ = lds + (bsel) + rbA + (rowoff) + (sz);          \
        _Pragma("unroll") for (int mi_ = 0; mi_ < 4; ++mi_)             \
            dst[mi_] = *(const f16x8*)(p_ + mi_ * 2048);                \
    }
    // B pieces (lo+hi) of one kk: 4 x ds_read_b128
#define RD_B(dlo, dhi, bsel, sz)                                        \
    {                                                                   \
        const char* p_ = lds + (bsel) + rbB + (sz);                     \
        _Pragma("unroll") for (int ni_ = 0; ni_ < 2; ++ni_) {           \
            dlo[ni_] = *(const f16x8*)(p_ + ni_ * 2048);                \
            dhi[ni_] = *(const f16x8*)(p_ + 4096 + ni_ * 2048);         \
        }                                                               \
    }

#define BARRIER __builtin_amdgcn_s_barrier()
#define LGKM(n) asm volatile("s_waitcnt lgkmcnt(" #n ")" ::: "memory")
#define SB0 __builtin_amdgcn_sched_barrier(0)
#define VM4 asm volatile("s_waitcnt vmcnt(4)" ::: "memory")

    // 16 MFMA: A-piece AF (4 mi) x B pieces BL (cols 0-1) / BH (cols 2-3)
#define MFC(AF, BL, BH, MOFF)                                                     \
    {                                                                             \
        __builtin_amdgcn_s_setprio(1);                                            \
        _Pragma("unroll") for (int mi_ = 0; mi_ < 4; ++mi_) {                     \
            _Pragma("unroll") for (int ni_ = 0; ni_ < 2; ++ni_) {                 \
                acc[(MOFF) + mi_][ni_] = __builtin_amdgcn_mfma_f32_16x16x32_f16(  \
                    AF[mi_], BL[ni_], acc[(MOFF) + mi_][ni_], 0, 0, 0);           \
                acc[(MOFF) + mi_][2 + ni_] = __builtin_amdgcn_mfma_f32_16x16x32_f16( \
                    AF[mi_], BH[ni_], acc[(MOFF) + mi_][2 + ni_], 0, 0, 0);       \
            }                                                                     \
        }                                                                         \
        __builtin_amdgcn_s_setprio(0);                                            \
    }

    f32x4 acc[8][4] = {};
    f16x8 aA[4], aB[4];           // ping-pong A pieces (16 regs each)
    f16x8 b0lo[2], b0hi[2];       // B k0 pieces
    f16x8 b1lo[2], b1hi[2];       // B k1 pieces
    const int b0 = 0, b1 = 65536;

    // ---- prologue: tile0 full + tile1 B halves; pre-read PH1's operand set ----
    ST(pAlo, 0, b0 + 0);
    ST(pAhi, 0, b0 + 16384);
    ST(pBlo, 0, b0 + 32768);
    ST(pBhi, 0, b0 + 49152);
    ST(pBlo, 1, b1 + 32768);
    ST(pBhi, 1, b1 + 49152);
    VM4;      // tile0's 8 loads retired; tile1's B outstanding(4)
    BARRIER;
    RD_A(aA, b0, 0, swz0);        // alo_k0(t0)
    RD_B(b0lo, b0hi, b0, swz0);   // B_k0(t0)
    // ds-queue: [8]

    for (int i = 0; i < NKT / 2; ++i) {
        const int t1s = 2 * i + 1;
        const int tp2 = (2 * i + 2 < NKT) ? 2 * i + 2 : NKT - 1;
        const int tp3 = (2 * i + 3 < NKT) ? 2 * i + 3 : NKT - 1;

        // ===== PH1: MFMA alo_k0(b0)·B_k0 ; read alo_k1+B_k1(b0) =====
        RD_A(aB, b0, 0, swz1);
        RD_B(b1lo, b1hi, b0, swz1);
        ST(pAlo, t1s, b1 + 0);
        BARRIER; LGKM(8); SB0;        // queue [prev8][new8] -> prev done
        MFC(aA, b0lo, b0hi, 0);
        BARRIER;

        // ===== PH2: MFMA alo_k1·B_k1 ; read ahi_k0(b0) =====
        RD_A(aA, b0, 8192, swz0);
        ST(pAhi, t1s, b1 + 16384);
        BARRIER; LGKM(4); SB0;        // queue [8][4] -> first 8 done
        MFC(aB, b1lo, b1hi, 0);
        BARRIER;

        // ===== PH3: MFMA ahi_k0·B_k0 ; read ahi_k1(b0) =====
        RD_A(aB, b0, 8192, swz1);
        ST(pBlo, tp2, b0 + 32768);
        BARRIER; LGKM(4); SB0;        // queue [4][4] -> ahi_k0 done
        MFC(aA, b0lo, b0hi, 4);
        BARRIER;

        // ===== PH4: vmcnt(4)+barrier -> b1 landed; read alo_k0+B_k0(b1); MFMA ahi_k1·B_k1 =====
        ST(pBhi, tp2, b0 + 49152);
        VM4;                           // retires b1's A(t1s) + B(t1s) per ledger
        BARRIER;
        RD_A(aA, b1, 0, swz0);
        RD_B(b0lo, b0hi, b1, swz0);
        LGKM(8); SB0;                  // queue [ahi_k1 4][new 8] -> ahi_k1 done
        MFC(aB, b1lo, b1hi, 4);
        BARRIER;

        // ===== PH5: MFMA alo_k0(b1)·B_k0 ; read alo_k1+B_k1(b1) =====
        RD_A(aB, b1, 0, swz1);
        RD_B(b1lo, b1hi, b1, swz1);
        ST(pAlo, tp2, b0 + 0);
        BARRIER; LGKM(8); SB0;
        MFC(aA, b0lo, b0hi, 0);
        BARRIER;

        // ===== PH6: MFMA alo_k1·B_k1 ; read ahi_k0(b1) =====
        RD_A(aA, b1, 8192, swz0);
        ST(pAhi, tp2, b0 + 16384);
        BARRIER; LGKM(4); SB0;
        MFC(aB, b1lo, b1hi, 0);
        BARRIER;

        // ===== PH7: MFMA ahi_k0·B_k0 ; read ahi_k1(b1) =====
        RD_A(aB, b1, 8192, swz1);
        ST(pBlo, tp3, b1 + 32768);
        BARRIER; LGKM(4); SB0;
        MFC(aA, b0lo, b0hi, 4);
        BARRIER;

        // ===== PH8: vmcnt(4)+barrier -> b0 landed; read alo_k0+B_k0(b0); MFMA ahi_k1·B_k1 =====
        ST(pBhi, tp3, b1 + 49152);
        VM4;                           // retires b0's A(tp2)+B(tp2)
        BARRIER;
        RD_A(aA, b0, 0, swz0);
        RD_B(b0lo, b0hi, b0, swz0);
        LGKM(8); SB0;
        MFC(aB, b1lo, b1hi, 4);
        BARRIER;
    }
    asm volatile("s_waitcnt vmcnt(0) lgkmcnt(0)" ::: "memory");
    __syncthreads();

    // ---- epilogue: LDS transpose -> float4 stores ----
    const float4 b4 = *(const float4*)&bias[n0 + lane * 4];
    float* wbase = (float*)lds + wv * 1088;  // 16 rows x 68 f32
#pragma unroll
    for (int mi = 0; mi < 8; ++mi) {
        __syncthreads();
#pragma unroll
        for (int ni = 0; ni < 4; ++ni)
#pragma unroll
            for (int j = 0; j < 4; ++j)
                wbase[(lg * 4 + j) * 68 + ni * 16 + lr] = acc[mi][ni][j];
        __syncthreads();
#pragma unroll
        for (int k = 0; k < 4; ++k) {
            int rr = wv * 4 + k;        // 0..31
            int wmp = rr >> 4, r16 = rr & 15;
            size_t mg = m0 + wmp * 128 + mi * 16 + r16;
            float axv = ax[mg];
            int wvp = wmp * 4 + (lane >> 4);
            float4 v = *(const float4*)((const float*)lds + wvp * 1088 + r16 * 68 + (lane & 15) * 4);
            float4 o;
            o.x = v.x * axv + b4.x;
            o.y = v.y * axv + b4.y;
            o.z = v.z * axv + b4.z;
            o.w = v.w * axv + b4.w;
            *(float4*)&C[mg * (size_t)N + n0 + lane * 4] = o;
        }
    }
}

extern "C" void kernel_launch(void* const* d_in, const int* in_sizes, int n_in,
                              void* d_out, int out_size, void* d_ws, size_t ws_size,
                              hipStream_t stream) {
    const float* x = (const float*)d_in[0];
    const float* w = (const float*)d_in[1];
    const float* bias = (const float*)d_in[2];
    float* out = (float*)d_out;

    const int M = in_sizes[0] / K_DIM;  // 8192
    const int N = NF_DIM;

    char* ws = (char*)d_ws;
    f16* qx = (f16*)ws;
    f16* wqt = (f16*)(ws + (size_t)M * KPAD * 2);
    float* ax = (float*)(ws + (size_t)M * KPAD * 2 + (size_t)N * KPAD * 2);
    float* sw = ax + M;

    quant_x_kernel<<<M, 256, 0, stream>>>(x, qx, ax);
    wscale_kernel<<<K_DIM, 256, 0, stream>>>(w, sw);
    wtq_kernel<<<dim3(KPAD / 64, NF_DIM / 64), 256, 0, stream>>>(w, sw, wqt);

    (void)hipFuncSetAttribute((const void*)gemm256,
                              hipFuncAttributeMaxDynamicSharedMemorySize, 131072);
    gemm256<<<(M / 256) * (N / 256), 512, 131072, stream>>>(qx, wqt, ax, bias, out, M, N);
}